// Round 5
// baseline (199.447 us; speedup 1.0000x reference)
//
#include <hip/hip_runtime.h>

// entmax-1.5 attention via f16 MFMA, round 5.
// B*H=16 heads, S=2048, D=128, fp32 I/O. Block = 512 threads (8 waves), 32 q.
//
// Prepass: K -> K16 (f16 row-major), V -> V16T (f16 transposed [d][k]).
// Phase A: swapped QK^T (A=K, B=Q) with mfma_f32_32x32x16_f16.
//   K fragments loaded DIRECTLY global->reg (16B dwordx4, L2-resident),
//   2-tile register double buffer, no LDS, no barriers.
// Phase B: row max + 8 Newton iters for tau on packed f16 z (v_dot2_f32_f16).
// Phase C/D: p=(z-tau)^2 -> f16 LDS chunks (XOR-swizzled); producer wave c+1
//   fills buf[(c+1)&1] while all waves consume chunk c with
//   mfma_f32_16x16x32_f16; V fragment = one 16B load from V16T.

constexpr int S = 2048;
constexpr int D = 128;
constexpr int NH = 16;

typedef _Float16 f16x8 __attribute__((ext_vector_type(8)));
typedef _Float16 f16x4 __attribute__((ext_vector_type(4)));
typedef _Float16 v2h   __attribute__((ext_vector_type(2)));
typedef __fp16   fp16x2 __attribute__((ext_vector_type(2)));
typedef float f32x4  __attribute__((ext_vector_type(4)));
typedef float f32x16 __attribute__((ext_vector_type(16)));

union H8 { f16x8 v; fp16x2 h[4]; };
union PK { fp16x2 a; v2h b; };

__device__ __forceinline__ f16x8 cvt8(float4 a, float4 b) {
  H8 r;
  r.h[0] = __builtin_amdgcn_cvt_pkrtz(a.x, a.y);
  r.h[1] = __builtin_amdgcn_cvt_pkrtz(a.z, a.w);
  r.h[2] = __builtin_amdgcn_cvt_pkrtz(b.x, b.y);
  r.h[3] = __builtin_amdgcn_cvt_pkrtz(b.z, b.w);
  return r.v;
}

// ---- prepass: K16 row-major + V^T f16 ----
__global__ __launch_bounds__(256)
void prepass(const float* __restrict__ K, const float* __restrict__ V,
             _Float16* __restrict__ K16, _Float16* __restrict__ V16T) {
  const int tid  = threadIdx.x;
  const int head = blockIdx.y;
  const int k0   = blockIdx.x * 128;
  const float* Kh = K + (size_t)head * S * D + (size_t)k0 * D;
  const float* Vh = V + (size_t)head * S * D + (size_t)k0 * D;
  _Float16* K16h  = K16 + (size_t)head * S * D + (size_t)k0 * D;
  _Float16* V16Th = V16T + (size_t)head * S * D;   // [d][k], row stride S

  // K: 128 rows x 32 float4 chunks = 4096 / 256 threads = 16 iters (coalesced)
#pragma unroll
  for (int it = 0; it < 16; ++it) {
    int idx = it * 256 + tid;
    float4 a = reinterpret_cast<const float4*>(Kh)[idx];
    f16x4 o = {(_Float16)a.x, (_Float16)a.y, (_Float16)a.z, (_Float16)a.w};
    reinterpret_cast<f16x4*>(K16h)[idx] = o;
  }
  // V^T: thread handles fixed d, 8 consecutive k; reads coalesced (lanes span d)
#pragma unroll
  for (int p = 0; p < 8; ++p) {
    int kg = p * 2 + (tid >> 7);   // 0..15
    int d  = tid & 127;
    f16x8 o;
#pragma unroll
    for (int i = 0; i < 8; ++i)
      o[i] = (_Float16)Vh[(size_t)(kg * 8 + i) * D + d];
    *(f16x8*)(V16Th + (size_t)d * S + k0 + kg * 8) = o;
  }
}

template<bool F16>
__device__ __forceinline__ f16x8 loadKfrag(const void* base, int elemOff) {
  if constexpr (F16) {
    return *(const f16x8*)((const _Float16*)base + elemOff);
  } else {
    const float* p = (const float*)base + elemOff;
    return cvt8(*(const float4*)p, *(const float4*)(p + 4));
  }
}

template<bool F16>
__global__ __launch_bounds__(512, 2)
void entmax_attn(const float* __restrict__ Q, const float* __restrict__ K,
                 const float* __restrict__ V, const _Float16* __restrict__ K16,
                 const _Float16* __restrict__ V16T, float* __restrict__ O) {
  __shared__ __align__(16) char smem[32768];   // 2 x 16KB P chunks
  __shared__ float  redmax[8][32];
  __shared__ float2 redfg[2][8][32];

  const int tid  = threadIdx.x;
  const int lane = tid & 63;
  const int wid  = tid >> 6;
  const int l31  = lane & 31;
  const int h    = lane >> 5;
  const int q16  = lane & 15;
  const int g4   = lane >> 4;

  // XCD-aware mapping: 2 heads per XCD -> K16/V16T resident in per-XCD L2.
  const int bi   = blockIdx.x;
  const int head = (bi & 7) * 2 + ((bi >> 3) >> 6);
  const int qb   = ((bi >> 3) & 63) * 32;

  const size_t hb = (size_t)head * S * D;
  const float* Qh = Q + hb;
  const float* Vh = V + hb;
  float* Oh = O + hb;

  const size_t koff = (size_t)(wid * 256 + l31) * D + 8 * h;
  const void* kb = F16 ? (const void*)(K16 + hb + koff) : (const void*)(K + hb + koff);
  const _Float16* vt = V16T + hb + (size_t)(wid * 16 + q16) * S;

  // ---- Q fragments (persistent): B[d][q], q = l31, d = ds*16 + 8h + i ----
  f16x8 qf[8];
  {
    const float* qr = Qh + (size_t)(qb + l31) * D + 8 * h;
#pragma unroll
    for (int ds = 0; ds < 8; ++ds) {
      float4 a = *(const float4*)(qr + ds * 16);
      float4 b = *(const float4*)(qr + ds * 16 + 4);
      qf[ds] = cvt8(a, b);
    }
  }

  // ---- Phase A: scores, direct-from-L2 K fragments, 2-tile reg dbuf ----
  f32x16 acc[8];
#pragma unroll
  for (int t = 0; t < 8; ++t)
#pragma unroll
    for (int e = 0; e < 16; ++e) acc[t][e] = 0.f;

  f16x8 kfA[8], kfB[8];
#pragma unroll
  for (int ds = 0; ds < 8; ++ds) kfA[ds] = loadKfrag<F16>(kb, 0 * 4096 + ds * 16);
#pragma unroll
  for (int ds = 0; ds < 8; ++ds) kfB[ds] = loadKfrag<F16>(kb, 1 * 4096 + ds * 16);

#pragma unroll
  for (int t = 0; t < 8; t += 2) {
#pragma unroll
    for (int ds = 0; ds < 8; ++ds) {
      acc[t] = __builtin_amdgcn_mfma_f32_32x32x16_f16(kfA[ds], qf[ds], acc[t], 0, 0, 0);
      if (t + 2 < 8) kfA[ds] = loadKfrag<F16>(kb, (t + 2) * 4096 + ds * 16);
    }
#pragma unroll
    for (int ds = 0; ds < 8; ++ds) {
      acc[t + 1] = __builtin_amdgcn_mfma_f32_32x32x16_f16(kfB[ds], qf[ds], acc[t + 1], 0, 0, 0);
      if (t + 3 < 8) kfB[ds] = loadKfrag<F16>(kb, (t + 3) * 4096 + ds * 16);
    }
  }

  // ---- Phase B: row max -> packed f16 z -> Newton for tau ----
  const float hs = 0.04419417382415922f;  // 0.5 / sqrt(128)
  float mx = -3.4e38f;
#pragma unroll
  for (int t = 0; t < 8; ++t)
#pragma unroll
    for (int e = 0; e < 16; ++e) mx = fmaxf(mx, acc[t][e]);
  mx = fmaxf(mx, __shfl_xor(mx, 32));
  if (lane < 32) redmax[wid][l31] = mx;
  __syncthreads();
  float m = redmax[0][l31];
#pragma unroll
  for (int w = 1; w < 8; ++w) m = fmaxf(m, redmax[w][l31]);

  const float bz = -m * hs;
  v2h z16[64];
#pragma unroll
  for (int t = 0; t < 8; ++t)
#pragma unroll
    for (int j = 0; j < 8; ++j) {
      float a0 = fmaf(acc[t][2 * j], hs, bz);
      float a1 = fmaf(acc[t][2 * j + 1], hs, bz);
      PK pk; pk.a = __builtin_amdgcn_cvt_pkrtz(a0, a1);
      z16[t * 8 + j] = pk.b;
    }

  const v2h zero2 = {(_Float16)0.f, (_Float16)0.f};
  const v2h one2  = {(_Float16)1.f, (_Float16)1.f};
  float tau = -1.f;
  for (int it = 0; it < 8; ++it) {
    const _Float16 th = (_Float16)tau;
    const v2h tt = {th, th};
    float f = 0.f, g = 0.f;
#pragma unroll
    for (int j = 0; j < 64; ++j) {
      v2h d = __builtin_elementwise_max(z16[j] - tt, zero2);
#if __has_builtin(__builtin_amdgcn_fdot2)
      f = __builtin_amdgcn_fdot2(d, d, f, false);
      g = __builtin_amdgcn_fdot2(d, one2, g, false);
#else
      float d0 = (float)d[0], d1 = (float)d[1];
      f = fmaf(d0, d0, fmaf(d1, d1, f));
      g += d0 + d1;
#endif
    }
    f += __shfl_xor(f, 32);
    g += __shfl_xor(g, 32);
    if (lane < 32) redfg[it & 1][wid][l31] = make_float2(f, g);
    __syncthreads();
    f = 0.f; g = 0.f;
#pragma unroll
    for (int w = 0; w < 8; ++w) {
      float2 r = redfg[it & 1][w][l31];
      f += r.x; g += r.y;
    }
    tau += (f - 1.f) / (2.f * fmaxf(g, 1e-20f));
  }

  // ---- write this wave's P chunk (32q x 256k f16, XOR-swizzled rows) ----
  auto writeP = [&](int buf) {
    char* pb = smem + buf * 16384;
    const int sw = (l31 & 7) << 4;
    const _Float16 th = (_Float16)tau;
    const v2h tt = {th, th};
#pragma unroll
    for (int t = 0; t < 8; ++t) {
#pragma unroll
      for (int j = 0; j < 8; ++j) {
        v2h d = __builtin_elementwise_max(z16[t * 8 + j] - tt, zero2);
        v2h p = d * d;
        const int r0 = 2 * j;
        const int k = t * 32 + 8 * (r0 >> 2) + 4 * h + (r0 & 3);
        const int off = (l31 * 512 + k * 2) ^ sw;
        *(v2h*)(pb + off) = p;
      }
    }
  };

  // ---- Phase D: Out = P V, streamed over 8 chunks ----
  f32x4 oa0[2] = {{0.f, 0.f, 0.f, 0.f}, {0.f, 0.f, 0.f, 0.f}};
  f32x4 oa1[2] = {{0.f, 0.f, 0.f, 0.f}, {0.f, 0.f, 0.f, 0.f}};
  const int sw = (q16 & 7) << 4;

  if (wid == 0) writeP(0);
  __syncthreads();

  for (int c = 0; c < 8; ++c) {
    if (wid == c + 1) writeP((c + 1) & 1);
    const char* pb = smem + (c & 1) * 16384;
#pragma unroll
    for (int ks = 0; ks < 8; ++ks) {
      H8 bf;
      if constexpr (F16) {
        bf.v = *(const f16x8*)(vt + c * 256 + ks * 32 + 8 * g4);
      } else {
        const float* vp = Vh + (size_t)(c * 256 + ks * 32 + 8 * g4) * D + wid * 16 + q16;
        float v0 = vp[0 * D], v1 = vp[1 * D], v2 = vp[2 * D], v3 = vp[3 * D];
        float v4 = vp[4 * D], v5 = vp[5 * D], v6 = vp[6 * D], v7 = vp[7 * D];
        bf.h[0] = __builtin_amdgcn_cvt_pkrtz(v0, v1);
        bf.h[1] = __builtin_amdgcn_cvt_pkrtz(v2, v3);
        bf.h[2] = __builtin_amdgcn_cvt_pkrtz(v4, v5);
        bf.h[3] = __builtin_amdgcn_cvt_pkrtz(v6, v7);
      }
      const int ob = ks * 64 + g4 * 16;
      f16x8 A0 = *(const f16x8*)(pb + ((q16 * 512 + ob) ^ sw));
      f16x8 A1 = *(const f16x8*)(pb + (((q16 + 16) * 512 + ob) ^ sw));
      oa0[ks & 1] = __builtin_amdgcn_mfma_f32_16x16x32_f16(A0, bf.v, oa0[ks & 1], 0, 0, 0);
      oa1[ks & 1] = __builtin_amdgcn_mfma_f32_16x16x32_f16(A1, bf.v, oa1[ks & 1], 0, 0, 0);
    }
    __syncthreads();
  }

  // ---- store: C layout col = q16 = d-in-tile, row = 4*g4 + r ----
  float* op = Oh + (size_t)(qb + 4 * g4) * D + wid * 16 + q16;
#pragma unroll
  for (int r = 0; r < 4; ++r) {
    op[(size_t)r * D]        = oa0[0][r] + oa0[1][r];
    op[(size_t)(16 + r) * D] = oa1[0][r] + oa1[1][r];
  }
}

extern "C" void kernel_launch(void* const* d_in, const int* in_sizes, int n_in,
                              void* d_out, int out_size, void* d_ws, size_t ws_size,
                              hipStream_t stream) {
  const float* q = (const float*)d_in[0];
  const float* k = (const float*)d_in[1];
  const float* v = (const float*)d_in[2];
  float* out = (float*)d_out;

  const size_t nelem = (size_t)NH * S * D;            // 4.19M per tensor
  const size_t need  = nelem * 2 * sizeof(_Float16);  // K16 + V16T = 16.8MB
  dim3 grid(1024, 1, 1), block(512, 1, 1);

  if (ws_size >= need) {
    _Float16* k16  = (_Float16*)d_ws;
    _Float16* v16t = k16 + nelem;
    prepass<<<dim3(16, NH), dim3(256), 0, stream>>>(k, v, k16, v16t);
    entmax_attn<true><<<grid, block, 0, stream>>>(q, k, v, k16, v16t, out);
  } else {
    entmax_attn<false><<<grid, block, 0, stream>>>(q, k, v, nullptr, nullptr, out);
  }
}

// Round 6
// 142.203 us; speedup vs baseline: 1.4026x; 1.4026x over previous
//
#include <hip/hip_runtime.h>

// entmax-1.5 attention, round 6: all-register PV via sigma-permuted fragments.
// B*H=16 heads, S=2048, D=128, fp32 I/O. Block = 512 threads (8 waves), 32 q.
//
// Prepass: K -> K16F in MFMA A-fragment layout with row-permutation
//   sigma(r) = swap bits 2,3 of r, so that QK^T C-registers are directly
//   PV B-fragments. V -> V16T2 in PV A-fragment layout ([kappa][dt][h][dd][i]).
// Phase A: swapped QK^T (A=K,B=Q*hs) mfma_f32_32x32x16_f16; K frags loaded
//   coalesced (1KB/instr) global->reg, 2-tile register double buffer. No LDS.
// Phase B: row max + 8 Newton iters for tau on packed f16 z (v_dot2_f32_f16).
// Phase C: p=(z-tau)^2 in-place packed -> pp == PV B-fragments (no exchange!).
// Phase D: O^T = V^T P per wave k-slice: 64 reg-only MFMAs, V frags coalesced.
// Phase E: cross-wave k-sum via 3-round LDS tree (swizzled) + coop store.

constexpr int S = 2048;
constexpr int D = 128;
constexpr int NH = 16;

typedef _Float16 f16x8 __attribute__((ext_vector_type(8)));
typedef _Float16 v2h   __attribute__((ext_vector_type(2)));
typedef __fp16   fp16x2 __attribute__((ext_vector_type(2)));
typedef float f32x4  __attribute__((ext_vector_type(4)));
typedef float f32x16 __attribute__((ext_vector_type(16)));

union H8 { f16x8 v; fp16x2 h[4]; };
union PK { fp16x2 a; v2h b; };
union Z  { f16x8 f8[16]; v2h v2[64]; };

__device__ __forceinline__ f16x8 cvt8(float4 a, float4 b) {
  H8 r;
  r.h[0] = __builtin_amdgcn_cvt_pkrtz(a.x, a.y);
  r.h[1] = __builtin_amdgcn_cvt_pkrtz(a.z, a.w);
  r.h[2] = __builtin_amdgcn_cvt_pkrtz(b.x, b.y);
  r.h[3] = __builtin_amdgcn_cvt_pkrtz(b.z, b.w);
  return r.v;
}

// ---- prepass: K16F (sigma-permuted A-frag layout) + V16T2 (PV A-frag) ----
__global__ __launch_bounds__(256)
void prepass(const float* __restrict__ K, const float* __restrict__ V,
             _Float16* __restrict__ K16F, _Float16* __restrict__ V16T2) {
  __shared__ float tile[32][128];
  const int tid  = threadIdx.x;
  const int tb   = blockIdx.x;     // 32-row k-tile, 0..63
  const int head = blockIdx.y;
  const size_t hb = (size_t)head * S * D;
  const float* Kt = K + hb + (size_t)tb * 32 * D;
  const float* Vt = V + hb + (size_t)tb * 32 * D;

#pragma unroll
  for (int it = 0; it < 4; ++it) {
    int idx = it * 256 + tid;               // 0..1023 float4 chunks
    int row = idx >> 5, c = idx & 31;
    *(float4*)&tile[row][c * 4] = *(const float4*)(Kt + (size_t)row * D + c * 4);
  }
  __syncthreads();
  // K16F element (tau, g=ds*2+h, r, i) = K[tau*32 + sigma(r)][ds*16 + 8h + i]
#pragma unroll
  for (int it = 0; it < 2; ++it) {
    int s = it * 256 + tid;                 // (g)*32 + r, g=0..15
    int r = s & 31, g = s >> 5;
    int ds = g >> 1, hh = g & 1;
    int sr = (r & 19) | ((r & 4) << 1) | ((r & 8) >> 1);   // swap bits 2,3
    const float* src = &tile[sr][ds * 16 + 8 * hh];
    f16x8 o;
#pragma unroll
    for (int i = 0; i < 8; ++i) o[i] = (_Float16)src[i];
    *(f16x8*)(K16F + ((size_t)(head * 64 + tb) * 16 + g) * 256 + r * 8) = o;
  }
  __syncthreads();
#pragma unroll
  for (int it = 0; it < 4; ++it) {
    int idx = it * 256 + tid;
    int row = idx >> 5, c = idx & 31;
    *(float4*)&tile[row][c * 4] = *(const float4*)(Vt + (size_t)row * D + c * 4);
  }
  __syncthreads();
  // V16T2 element (kappa, dt, h, dd, i) = V[kappa*16 + 8h + i][dt*32 + dd]
#pragma unroll
  for (int it = 0; it < 2; ++it) {
    int s = it * 256 + tid;
    int dd = s & 31, g = s >> 5;            // g = (kl*4+dt)*2+h
    int hh = g & 1, dt = (g >> 1) & 3, kl = g >> 3;
    f16x8 o;
#pragma unroll
    for (int i = 0; i < 8; ++i) o[i] = (_Float16)tile[kl * 16 + 8 * hh + i][dt * 32 + dd];
    *(f16x8*)(V16T2 + (((size_t)(head * 128 + tb * 2 + kl) * 4 + dt) * 2 + hh) * 256 + dd * 8) = o;
  }
}

__global__ __launch_bounds__(512, 2)
void entmax_attn(const float* __restrict__ Q, const _Float16* __restrict__ K16F,
                 const _Float16* __restrict__ V16T2, float* __restrict__ O) {
  __shared__ __align__(16) char smem[65536];   // 4 x 16KB O-reduce regions
  __shared__ float  redmax[8][32];
  __shared__ float2 redfg[2][8][32];

  const int tid  = threadIdx.x;
  const int lane = tid & 63;
  const int wid  = tid >> 6;
  const int l31  = lane & 31;
  const int h    = lane >> 5;

  // XCD-aware mapping: 2 heads per XCD -> K16F/V16T2 resident in per-XCD L2.
  const int bi   = blockIdx.x;
  const int head = (bi & 7) * 2 + ((bi >> 3) >> 6);
  const int qb   = ((bi >> 3) & 63) * 32;

  const size_t hb = (size_t)head * S * D;
  const float* Qh = Q + hb;
  float* Oh = O + hb;

  const _Float16* kfp = K16F + ((size_t)(head * 64 + wid * 8)) * 4096 + lane * 8;
  const _Float16* vfp = V16T2 + ((size_t)(head * 128 + wid * 16)) * 2048 + lane * 8;

  // ---- Q fragments (hs folded in): B[d][q], q=l31, d = ds*16 + 8h + i ----
  const float hs = 0.04419417382415922f;  // 0.5 / sqrt(128)
  f16x8 qf[8];
  {
    const float* qr = Qh + (size_t)(qb + l31) * D + 8 * h;
#pragma unroll
    for (int ds = 0; ds < 8; ++ds) {
      float4 a = *(const float4*)(qr + ds * 16);
      float4 b = *(const float4*)(qr + ds * 16 + 4);
      a.x *= hs; a.y *= hs; a.z *= hs; a.w *= hs;
      b.x *= hs; b.y *= hs; b.z *= hs; b.w *= hs;
      qf[ds] = cvt8(a, b);
    }
  }

  // ---- Phase A: scores (already x hs), coalesced K frags, 2-tile reg dbuf ----
  f32x16 acc[8];
#pragma unroll
  for (int t = 0; t < 8; ++t)
#pragma unroll
    for (int e = 0; e < 16; ++e) acc[t][e] = 0.f;

  f16x8 kA[8], kB[8];
#pragma unroll
  for (int ds = 0; ds < 8; ++ds) kA[ds] = *(const f16x8*)(kfp + 0 * 4096 + ds * 512);
#pragma unroll
  for (int ds = 0; ds < 8; ++ds) kB[ds] = *(const f16x8*)(kfp + 1 * 4096 + ds * 512);

#pragma unroll
  for (int t = 0; t < 8; t += 2) {
#pragma unroll
    for (int ds = 0; ds < 8; ++ds) {
      acc[t] = __builtin_amdgcn_mfma_f32_32x32x16_f16(kA[ds], qf[ds], acc[t], 0, 0, 0);
      if (t + 2 < 8) kA[ds] = *(const f16x8*)(kfp + (t + 2) * 4096 + ds * 512);
    }
#pragma unroll
    for (int ds = 0; ds < 8; ++ds) {
      acc[t + 1] = __builtin_amdgcn_mfma_f32_32x32x16_f16(kB[ds], qf[ds], acc[t + 1], 0, 0, 0);
      if (t + 3 < 8) kB[ds] = *(const f16x8*)(kfp + (t + 3) * 4096 + ds * 512);
    }
  }

  // ---- Phase B: row max -> packed f16 z = acc - m -> Newton for tau ----
  float mx = -3.4e38f;
#pragma unroll
  for (int t = 0; t < 8; ++t)
#pragma unroll
    for (int e = 0; e < 16; ++e) mx = fmaxf(mx, acc[t][e]);
  mx = fmaxf(mx, __shfl_xor(mx, 32));
  if (lane < 32) redmax[wid][l31] = mx;
  __syncthreads();
  float m = redmax[0][l31];
#pragma unroll
  for (int w = 1; w < 8; ++w) m = fmaxf(m, redmax[w][l31]);

  Z z;
#pragma unroll
  for (int t = 0; t < 8; ++t)
#pragma unroll
    for (int j = 0; j < 8; ++j) {
      PK pk;
      pk.a = __builtin_amdgcn_cvt_pkrtz(acc[t][2 * j] - m, acc[t][2 * j + 1] - m);
      z.v2[t * 8 + j] = pk.b;
    }

  const v2h zero2 = {(_Float16)0.f, (_Float16)0.f};
  const v2h one2  = {(_Float16)1.f, (_Float16)1.f};
  float tau = -1.f;
  for (int it = 0; it < 8; ++it) {
    const _Float16 th = (_Float16)tau;
    const v2h tt = {th, th};
    float f = 0.f, g = 0.f;
#pragma unroll
    for (int j = 0; j < 64; ++j) {
      v2h d = __builtin_elementwise_max(z.v2[j] - tt, zero2);
#if __has_builtin(__builtin_amdgcn_fdot2)
      f = __builtin_amdgcn_fdot2(d, d, f, false);
      g = __builtin_amdgcn_fdot2(d, one2, g, false);
#else
      float d0 = (float)d[0], d1 = (float)d[1];
      f = fmaf(d0, d0, fmaf(d1, d1, f));
      g += d0 + d1;
#endif
    }
    f += __shfl_xor(f, 32);
    g += __shfl_xor(g, 32);
    if (lane < 32) redfg[it & 1][wid][l31] = make_float2(f, g);
    __syncthreads();
    f = 0.f; g = 0.f;
#pragma unroll
    for (int w = 0; w < 8; ++w) {
      float2 r = redfg[it & 1][w][l31];
      f += r.x; g += r.y;
    }
    tau += (f - 1.f) / (2.f * fmaxf(g, 1e-20f));
  }

  // ---- Phase C: p = (z - tau)^2 in place; z.f8[kt] IS the PV B-fragment ----
  {
    const _Float16 th = (_Float16)tau;
    const v2h tt = {th, th};
#pragma unroll
    for (int j = 0; j < 64; ++j) {
      v2h d = __builtin_elementwise_max(z.v2[j] - tt, zero2);
      z.v2[j] = d * d;
    }
  }

  // ---- Phase D: O^T partial = V^T P over this wave's 256-k slice ----
  f32x16 oacc[4];
#pragma unroll
  for (int dt = 0; dt < 4; ++dt)
#pragma unroll
    for (int e = 0; e < 16; ++e) oacc[dt][e] = 0.f;

  f16x8 vf0[4], vf1[4];
#pragma unroll
  for (int dt = 0; dt < 4; ++dt) vf0[dt] = *(const f16x8*)(vfp + 0 * 2048 + dt * 512);

#pragma unroll
  for (int kt = 0; kt < 16; ++kt) {
    f16x8* cur = (kt & 1) ? vf1 : vf0;
    f16x8* nxt = (kt & 1) ? vf0 : vf1;
#pragma unroll
    for (int dt = 0; dt < 4; ++dt) {
      if (kt < 15) nxt[dt] = *(const f16x8*)(vfp + (kt + 1) * 2048 + dt * 512);
      oacc[dt] = __builtin_amdgcn_mfma_f32_32x32x16_f16(cur[dt], z.f8[kt], oacc[dt], 0, 0, 0);
    }
  }

  // ---- Phase E: cross-wave k-sum via LDS tree, then cooperative store ----
  // oacc[dt][e] = O[q=l31][d = dt*32 + (e&3) + 8*(e>>2) + 4h] (partial)
  float* ob = (float*)smem;
  auto wrO = [&](int reg) {
    char* b = (char*)(ob + reg * 4096);
#pragma unroll
    for (int dt = 0; dt < 4; ++dt)
#pragma unroll
      for (int eq = 0; eq < 4; ++eq) {
        int d0 = dt * 32 + 8 * eq + 4 * h;
        int by = l31 * 512 + ((d0 * 4) ^ ((l31 & 7) << 4));
        f32x4 v = {oacc[dt][eq * 4 + 0], oacc[dt][eq * 4 + 1],
                   oacc[dt][eq * 4 + 2], oacc[dt][eq * 4 + 3]};
        *(f32x4*)(b + by) = v;
      }
  };
  auto addO = [&](int reg) {
    const char* b = (const char*)(ob + reg * 4096);
#pragma unroll
    for (int dt = 0; dt < 4; ++dt)
#pragma unroll
      for (int eq = 0; eq < 4; ++eq) {
        int d0 = dt * 32 + 8 * eq + 4 * h;
        int by = l31 * 512 + ((d0 * 4) ^ ((l31 & 7) << 4));
        f32x4 v = *(const f32x4*)(b + by);
#pragma unroll
        for (int c = 0; c < 4; ++c) oacc[dt][eq * 4 + c] += v[c];
      }
  };

  __syncthreads();                       // Newton redfg done; smem reuse safe
  if (wid >= 4) wrO(wid - 4);
  __syncthreads();
  if (wid < 4) addO(wid);
  __syncthreads();
  if (wid == 2 || wid == 3) wrO(wid - 2);
  __syncthreads();
  if (wid < 2) addO(wid);
  __syncthreads();
  if (wid == 1) wrO(0);
  __syncthreads();
  if (wid == 0) { addO(0); wrO(0); }
  __syncthreads();

  {
    int q = tid >> 4, dq = tid & 15;
    const char* b0 = (const char*)ob;
    int by0 = q * 512 + ((dq * 32) ^ ((q & 7) << 4));
    int by1 = q * 512 + ((dq * 32 + 16) ^ ((q & 7) << 4));
    f32x4 v0 = *(const f32x4*)(b0 + by0);
    f32x4 v1 = *(const f32x4*)(b0 + by1);
    float* op = Oh + (size_t)(qb + q) * D + dq * 8;
    *(f32x4*)op = v0;
    *(f32x4*)(op + 4) = v1;
  }
}

extern "C" void kernel_launch(void* const* d_in, const int* in_sizes, int n_in,
                              void* d_out, int out_size, void* d_ws, size_t ws_size,
                              hipStream_t stream) {
  const float* q = (const float*)d_in[0];
  const float* k = (const float*)d_in[1];
  const float* v = (const float*)d_in[2];
  float* out = (float*)d_out;

  const size_t nelem = (size_t)NH * S * D;            // 4.19M per tensor
  _Float16* k16f  = (_Float16*)d_ws;
  _Float16* v16t2 = k16f + nelem;

  prepass<<<dim3(S / 32, NH), dim3(256), 0, stream>>>(k, v, k16f, v16t2);
  entmax_attn<<<dim3(1024), dim3(512), 0, stream>>>(q, k16f, v16t2, out);
}

// Round 7
// 137.849 us; speedup vs baseline: 1.4469x; 1.0316x over previous
//
#include <hip/hip_runtime.h>

// entmax-1.5 attention, round 7: dual-stripe phase pipelining.
// B*H=16 heads, S=2048, D=128, fp32 I/O. Block = 512 threads (8 waves), 64 q
// (two 32-q stripes). Grid = 512 (16 heads x 32 chunks, XCD-major).
//
// Prepass (r6, proven): K -> K16F sigma-permuted MFMA A-frag layout;
//   V -> V16T2 PV A-frag layout. QK^T C-regs are directly PV B-frags.
// Pipeline: A0 | z0 | B0(Newton0) ∥ A1 | z1 | B1(Newton1) ∥ D0(PV0) |
//   E0-write ∥ D1 part1 | E0-sum ∥ D1 part2 | E1.
// Newton stalls (8 barriers/stripe) are filled with the other stripe's
// MFMA + load work; endgame reductions overlap PV1.

constexpr int S = 2048;
constexpr int D = 128;
constexpr int NH = 16;

typedef _Float16 f16x8 __attribute__((ext_vector_type(8)));
typedef _Float16 v2h   __attribute__((ext_vector_type(2)));
typedef __fp16   fp16x2 __attribute__((ext_vector_type(2)));
typedef float f32x4  __attribute__((ext_vector_type(4)));
typedef float f32x16 __attribute__((ext_vector_type(16)));

union H8 { f16x8 v; fp16x2 h[4]; };
union PK { fp16x2 a; v2h b; };
union Z  { f16x8 f8[16]; v2h v2[64]; };

__device__ __forceinline__ f16x8 cvt8(float4 a, float4 b) {
  H8 r;
  r.h[0] = __builtin_amdgcn_cvt_pkrtz(a.x, a.y);
  r.h[1] = __builtin_amdgcn_cvt_pkrtz(a.z, a.w);
  r.h[2] = __builtin_amdgcn_cvt_pkrtz(b.x, b.y);
  r.h[3] = __builtin_amdgcn_cvt_pkrtz(b.z, b.w);
  return r.v;
}

// ---- prepass: K16F (sigma-permuted A-frag layout) + V16T2 (PV A-frag) ----
__global__ __launch_bounds__(256)
void prepass(const float* __restrict__ K, const float* __restrict__ V,
             _Float16* __restrict__ K16F, _Float16* __restrict__ V16T2) {
  __shared__ float tile[32][128];
  const int tid  = threadIdx.x;
  const int tb   = blockIdx.x;     // 32-row k-tile, 0..63
  const int head = blockIdx.y;
  const size_t hb = (size_t)head * S * D;
  const float* Kt = K + hb + (size_t)tb * 32 * D;
  const float* Vt = V + hb + (size_t)tb * 32 * D;

#pragma unroll
  for (int it = 0; it < 4; ++it) {
    int idx = it * 256 + tid;
    int row = idx >> 5, c = idx & 31;
    *(float4*)&tile[row][c * 4] = *(const float4*)(Kt + (size_t)row * D + c * 4);
  }
  __syncthreads();
#pragma unroll
  for (int it = 0; it < 2; ++it) {
    int s = it * 256 + tid;
    int r = s & 31, g = s >> 5;
    int ds = g >> 1, hh = g & 1;
    int sr = (r & 19) | ((r & 4) << 1) | ((r & 8) >> 1);   // swap bits 2,3
    const float* src = &tile[sr][ds * 16 + 8 * hh];
    f16x8 o;
#pragma unroll
    for (int i = 0; i < 8; ++i) o[i] = (_Float16)src[i];
    *(f16x8*)(K16F + ((size_t)(head * 64 + tb) * 16 + g) * 256 + r * 8) = o;
  }
  __syncthreads();
#pragma unroll
  for (int it = 0; it < 4; ++it) {
    int idx = it * 256 + tid;
    int row = idx >> 5, c = idx & 31;
    *(float4*)&tile[row][c * 4] = *(const float4*)(Vt + (size_t)row * D + c * 4);
  }
  __syncthreads();
#pragma unroll
  for (int it = 0; it < 2; ++it) {
    int s = it * 256 + tid;
    int dd = s & 31, g = s >> 5;
    int hh = g & 1, dt = (g >> 1) & 3, kl = g >> 3;
    f16x8 o;
#pragma unroll
    for (int i = 0; i < 8; ++i) o[i] = (_Float16)tile[kl * 16 + 8 * hh + i][dt * 32 + dd];
    *(f16x8*)(V16T2 + (((size_t)(head * 128 + tb * 2 + kl) * 4 + dt) * 2 + hh) * 256 + dd * 8) = o;
  }
}

__global__ __launch_bounds__(512, 2)
void entmax_attn(const float* __restrict__ Q, const _Float16* __restrict__ K16F,
                 const _Float16* __restrict__ V16T2, float* __restrict__ O) {
  __shared__ __align__(16) char oreg[131072];   // 8 x 16KB O-partial regions
  __shared__ float  redmax[8][32];
  __shared__ float2 redfg[2][8][32];

  const int tid  = threadIdx.x;
  const int lane = tid & 63;
  const int wid  = tid >> 6;
  const int l31  = lane & 31;
  const int h    = lane >> 5;

  const int bi   = blockIdx.x;
  const int head = (bi & 7) * 2 + ((bi >> 3) >> 5);
  const int qb0  = ((bi >> 3) & 31) * 64;
  const int qb1  = qb0 + 32;

  const size_t hb = (size_t)head * S * D;
  const float* Qh = Q + hb;
  float* Oh = O + hb;

  const _Float16* kfp = K16F + ((size_t)(head * 64 + wid * 8)) * 4096 + lane * 8;
  const _Float16* vfp = V16T2 + ((size_t)(head * 128 + wid * 16)) * 2048 + lane * 8;

  const float hs = 0.04419417382415922f;  // 0.5 / sqrt(128)
  const v2h zero2 = {(_Float16)0.f, (_Float16)0.f};
  const v2h one2  = {(_Float16)1.f, (_Float16)1.f};

  auto loadQ = [&](int qbase, f16x8* qf) {
    const float* qr = Qh + (size_t)(qbase + l31) * D + 8 * h;
#pragma unroll
    for (int ds = 0; ds < 8; ++ds) {
      float4 a = *(const float4*)(qr + ds * 16);
      float4 b = *(const float4*)(qr + ds * 16 + 4);
      a.x *= hs; a.y *= hs; a.z *= hs; a.w *= hs;
      b.x *= hs; b.y *= hs; b.z *= hs; b.w *= hs;
      qf[ds] = cvt8(a, b);
    }
  };

  // ================= Phase A0: QK^T stripe 0 =================
  f32x16 acc[8];
#pragma unroll
  for (int t = 0; t < 8; ++t)
#pragma unroll
    for (int e = 0; e < 16; ++e) acc[t][e] = 0.f;
  {
    f16x8 qfa[8];
    loadQ(qb0, qfa);
    f16x8 kA[8], kB[8];
#pragma unroll
    for (int ds = 0; ds < 8; ++ds) kA[ds] = *(const f16x8*)(kfp + 0 * 4096 + ds * 512);
#pragma unroll
    for (int ds = 0; ds < 8; ++ds) kB[ds] = *(const f16x8*)(kfp + 1 * 4096 + ds * 512);
#pragma unroll
    for (int t = 0; t < 8; t += 2) {
#pragma unroll
      for (int ds = 0; ds < 8; ++ds) {
        acc[t] = __builtin_amdgcn_mfma_f32_32x32x16_f16(kA[ds], qfa[ds], acc[t], 0, 0, 0);
        if (t + 2 < 8) kA[ds] = *(const f16x8*)(kfp + (t + 2) * 4096 + ds * 512);
      }
#pragma unroll
      for (int ds = 0; ds < 8; ++ds) {
        acc[t + 1] = __builtin_amdgcn_mfma_f32_32x32x16_f16(kB[ds], qfa[ds], acc[t + 1], 0, 0, 0);
        if (t + 3 < 8) kB[ds] = *(const f16x8*)(kfp + (t + 3) * 4096 + ds * 512);
      }
    }
  }

  // ---- redmax0 + z0 ----
  float mx = -3.4e38f;
#pragma unroll
  for (int t = 0; t < 8; ++t)
#pragma unroll
    for (int e = 0; e < 16; ++e) mx = fmaxf(mx, acc[t][e]);
  mx = fmaxf(mx, __shfl_xor(mx, 32));
  if (lane < 32) redmax[wid][l31] = mx;
  __syncthreads();
  float m0 = redmax[0][l31];
#pragma unroll
  for (int w = 1; w < 8; ++w) m0 = fmaxf(m0, redmax[w][l31]);

  Z z0;
#pragma unroll
  for (int t = 0; t < 8; ++t)
#pragma unroll
    for (int j = 0; j < 8; ++j) {
      PK pk;
      pk.a = __builtin_amdgcn_cvt_pkrtz(acc[t][2 * j] - m0, acc[t][2 * j + 1] - m0);
      z0.v2[t * 8 + j] = pk.b;
    }

  // ---- Q fragments stripe 1; re-zero acc for stripe 1 ----
  f16x8 qfb[8];
  loadQ(qb1, qfb);
#pragma unroll
  for (int t = 0; t < 8; ++t)
#pragma unroll
    for (int e = 0; e < 16; ++e) acc[t][e] = 0.f;

  // ================= B0 (Newton stripe 0) ∥ A1 (QK^T stripe 1) ============
  float tau0 = -1.f;
#pragma unroll
  for (int it = 0; it < 8; ++it) {
    f16x8 kb[8];
#pragma unroll
    for (int ds = 0; ds < 8; ++ds) kb[ds] = *(const f16x8*)(kfp + it * 4096 + ds * 512);
    const _Float16 th = (_Float16)tau0;
    const v2h tt = {th, th};
    float f = 0.f, g = 0.f;
#pragma unroll
    for (int j = 0; j < 64; ++j) {
      v2h d = __builtin_elementwise_max(z0.v2[j] - tt, zero2);
#if __has_builtin(__builtin_amdgcn_fdot2)
      f = __builtin_amdgcn_fdot2(d, d, f, false);
      g = __builtin_amdgcn_fdot2(d, one2, g, false);
#else
      float d0 = (float)d[0], d1 = (float)d[1];
      f = fmaf(d0, d0, fmaf(d1, d1, f));
      g += d0 + d1;
#endif
    }
    f += __shfl_xor(f, 32);
    g += __shfl_xor(g, 32);
    if (lane < 32) redfg[it & 1][wid][l31] = make_float2(f, g);
#pragma unroll
    for (int ds = 0; ds < 8; ++ds)
      acc[it] = __builtin_amdgcn_mfma_f32_32x32x16_f16(kb[ds], qfb[ds], acc[it], 0, 0, 0);
    __syncthreads();
    f = 0.f; g = 0.f;
#pragma unroll
    for (int w = 0; w < 8; ++w) {
      float2 r = redfg[it & 1][w][l31];
      f += r.x; g += r.y;
    }
    tau0 += (f - 1.f) / (2.f * fmaxf(g, 1e-20f));
  }

  // ---- redmax1 (p0 computed in the barrier gap) + z1 ----
  mx = -3.4e38f;
#pragma unroll
  for (int t = 0; t < 8; ++t)
#pragma unroll
    for (int e = 0; e < 16; ++e) mx = fmaxf(mx, acc[t][e]);
  mx = fmaxf(mx, __shfl_xor(mx, 32));
  if (lane < 32) redmax[wid][l31] = mx;
  {  // p0 = (z0 - tau0)^2 in place
    const _Float16 th = (_Float16)tau0;
    const v2h tt = {th, th};
#pragma unroll
    for (int j = 0; j < 64; ++j) {
      v2h d = __builtin_elementwise_max(z0.v2[j] - tt, zero2);
      z0.v2[j] = d * d;
    }
  }
  __syncthreads();
  float m1 = redmax[0][l31];
#pragma unroll
  for (int w = 1; w < 8; ++w) m1 = fmaxf(m1, redmax[w][l31]);

  Z z1;
#pragma unroll
  for (int t = 0; t < 8; ++t)
#pragma unroll
    for (int j = 0; j < 8; ++j) {
      PK pk;
      pk.a = __builtin_amdgcn_cvt_pkrtz(acc[t][2 * j] - m1, acc[t][2 * j + 1] - m1);
      z1.v2[t * 8 + j] = pk.b;
    }

  // ================= B1 (Newton stripe 1) ∥ D0 (PV stripe 0) ==============
  f32x16 oacc[4];
#pragma unroll
  for (int dt = 0; dt < 4; ++dt)
#pragma unroll
    for (int e = 0; e < 16; ++e) oacc[dt][e] = 0.f;

  float tau1 = -1.f;
#pragma unroll
  for (int it = 0; it < 8; ++it) {
    f16x8 va[4], vb[4];
#pragma unroll
    for (int dt = 0; dt < 4; ++dt) va[dt] = *(const f16x8*)(vfp + (2 * it) * 2048 + dt * 512);
#pragma unroll
    for (int dt = 0; dt < 4; ++dt) vb[dt] = *(const f16x8*)(vfp + (2 * it + 1) * 2048 + dt * 512);
    const _Float16 th = (_Float16)tau1;
    const v2h tt = {th, th};
    float f = 0.f, g = 0.f;
#pragma unroll
    for (int j = 0; j < 64; ++j) {
      v2h d = __builtin_elementwise_max(z1.v2[j] - tt, zero2);
#if __has_builtin(__builtin_amdgcn_fdot2)
      f = __builtin_amdgcn_fdot2(d, d, f, false);
      g = __builtin_amdgcn_fdot2(d, one2, g, false);
#else
      float d0 = (float)d[0], d1 = (float)d[1];
      f = fmaf(d0, d0, fmaf(d1, d1, f));
      g += d0 + d1;
#endif
    }
    f += __shfl_xor(f, 32);
    g += __shfl_xor(g, 32);
    if (lane < 32) redfg[it & 1][wid][l31] = make_float2(f, g);
#pragma unroll
    for (int dt = 0; dt < 4; ++dt)
      oacc[dt] = __builtin_amdgcn_mfma_f32_32x32x16_f16(va[dt], z0.f8[2 * it], oacc[dt], 0, 0, 0);
#pragma unroll
    for (int dt = 0; dt < 4; ++dt)
      oacc[dt] = __builtin_amdgcn_mfma_f32_32x32x16_f16(vb[dt], z0.f8[2 * it + 1], oacc[dt], 0, 0, 0);
    __syncthreads();
    f = 0.f; g = 0.f;
#pragma unroll
    for (int w = 0; w < 8; ++w) {
      float2 r = redfg[it & 1][w][l31];
      f += r.x; g += r.y;
    }
    tau1 += (f - 1.f) / (2.f * fmaxf(g, 1e-20f));
  }

  // ---- p1 in place ----
  {
    const _Float16 th = (_Float16)tau1;
    const v2h tt = {th, th};
#pragma unroll
    for (int j = 0; j < 64; ++j) {
      v2h d = __builtin_elementwise_max(z1.v2[j] - tt, zero2);
      z1.v2[j] = d * d;
    }
  }

  // ================= Endgame: E0 ∥ D1, then E1 =================
  auto writeO = [&]() {
    char* b = oreg + wid * 16384;
#pragma unroll
    for (int dt = 0; dt < 4; ++dt)
#pragma unroll
      for (int eq = 0; eq < 4; ++eq) {
        int d0 = dt * 32 + 8 * eq + 4 * h;
        int by = l31 * 512 + ((d0 * 4) ^ ((l31 & 7) << 4));
        f32x4 v = {oacc[dt][eq * 4 + 0], oacc[dt][eq * 4 + 1],
                   oacc[dt][eq * 4 + 2], oacc[dt][eq * 4 + 3]};
        *(f32x4*)(b + by) = v;
      }
  };
  auto sumStore = [&](int qbase) {
    int q = tid >> 4, dq = tid & 15;
    int by0 = q * 512 + ((dq * 32) ^ ((q & 7) << 4));
    int by1 = q * 512 + ((dq * 32 + 16) ^ ((q & 7) << 4));
    f32x4 s0 = {0.f, 0.f, 0.f, 0.f}, s1 = {0.f, 0.f, 0.f, 0.f};
#pragma unroll
    for (int r = 0; r < 8; ++r) {
      const char* b = oreg + r * 16384;
      f32x4 v0 = *(const f32x4*)(b + by0);
      f32x4 v1 = *(const f32x4*)(b + by1);
#pragma unroll
      for (int c = 0; c < 4; ++c) { s0[c] += v0[c]; s1[c] += v1[c]; }
    }
    float* op = Oh + (size_t)(qbase + q) * D + dq * 8;
    *(f32x4*)op = s0;
    *(f32x4*)(op + 4) = s1;
  };

  writeO();                 // stripe-0 partials -> regions
#pragma unroll
  for (int dt = 0; dt < 4; ++dt)
#pragma unroll
    for (int e = 0; e < 16; ++e) oacc[dt][e] = 0.f;

  f16x8 vf0[4], vf1[4];
#pragma unroll
  for (int dt = 0; dt < 4; ++dt) vf0[dt] = *(const f16x8*)(vfp + 0 * 2048 + dt * 512);
#pragma unroll
  for (int kt = 0; kt < 16; ++kt) {
    if (kt == 8) { __syncthreads(); sumStore(qb0); }
    f16x8* cur = (kt & 1) ? vf1 : vf0;
    f16x8* nxt = (kt & 1) ? vf0 : vf1;
#pragma unroll
    for (int dt = 0; dt < 4; ++dt) {
      if (kt < 15) nxt[dt] = *(const f16x8*)(vfp + (kt + 1) * 2048 + dt * 512);
      oacc[dt] = __builtin_amdgcn_mfma_f32_32x32x16_f16(cur[dt], z1.f8[kt], oacc[dt], 0, 0, 0);
    }
  }
  __syncthreads();          // sumStore(qb0) reads done; oacc1 complete
  writeO();                 // stripe-1 partials -> regions
  __syncthreads();
  sumStore(qb1);
}

extern "C" void kernel_launch(void* const* d_in, const int* in_sizes, int n_in,
                              void* d_out, int out_size, void* d_ws, size_t ws_size,
                              hipStream_t stream) {
  const float* q = (const float*)d_in[0];
  const float* k = (const float*)d_in[1];
  const float* v = (const float*)d_in[2];
  float* out = (float*)d_out;

  const size_t nelem = (size_t)NH * S * D;
  _Float16* k16f  = (_Float16*)d_ws;
  _Float16* v16t2 = k16f + nelem;

  prepass<<<dim3(S / 32, NH), dim3(256), 0, stream>>>(k, v, k16f, v16t2);
  entmax_attn<<<dim3(512), dim3(512), 0, stream>>>(q, k16f, v16t2, out);
}

// Round 8
// 118.991 us; speedup vs baseline: 1.6761x; 1.1585x over previous
//
#include <hip/hip_runtime.h>

// entmax-1.5 attention, round 8: wave-local Newton via one-shot z redistribution.
// B*H=16 heads, S=2048, D=128, fp32 I/O. Block = 512 threads (8 waves), 32 q.
// Grid = 1024 (16 heads x 64 q-chunks, XCD-major).
//
// Prepass (r6, proven): K -> K16F sigma-permuted MFMA A-frag layout;
//   V -> V16T2 PV A-frag layout. QK^T C-regs are directly PV B-frags.
// Phase A: swapped QK^T (A=K,B=Q*hs) mfma_f32_32x32x16_f16, coalesced K frags,
//   2-tile register double buffer. No LDS.
// Phase R: z (f16, NO max-sub - entmax is shift-invariant) -> zbuf[32][2048]
//   (swizzled), ONE barrier. Each wave re-reads 4 complete q-rows into regs.
// Phase B: row max + 8 Newton iters, ALL wave-local (shfl over 16 lanes,
//   tau0 = rowmax - 1). tau -> taubuf, ONE barrier.
// Phase C/D: p=(z-tau)^2 in holder sigma-layout regs; PV all-register
//   (64 MFMA), V frags coalesced from V16T2.
// Phase E: 8-region O-partial write (oreg aliases zbuf) + cooperative sum.
// Barriers per block: 3 (vs ~20 in r7).

constexpr int S = 2048;
constexpr int D = 128;
constexpr int NH = 16;

typedef _Float16 f16x8 __attribute__((ext_vector_type(8)));
typedef _Float16 v2h   __attribute__((ext_vector_type(2)));
typedef __fp16   fp16x2 __attribute__((ext_vector_type(2)));
typedef float f32x4  __attribute__((ext_vector_type(4)));
typedef float f32x16 __attribute__((ext_vector_type(16)));

union H8 { f16x8 v; fp16x2 h[4]; };
union PK { fp16x2 a; v2h b; };
union Z  { f16x8 f8[16]; v2h v2[64]; };

__device__ __forceinline__ f16x8 cvt8(float4 a, float4 b) {
  H8 r;
  r.h[0] = __builtin_amdgcn_cvt_pkrtz(a.x, a.y);
  r.h[1] = __builtin_amdgcn_cvt_pkrtz(a.z, a.w);
  r.h[2] = __builtin_amdgcn_cvt_pkrtz(b.x, b.y);
  r.h[3] = __builtin_amdgcn_cvt_pkrtz(b.z, b.w);
  return r.v;
}

// ---- prepass: K16F (sigma-permuted A-frag layout) + V16T2 (PV A-frag) ----
__global__ __launch_bounds__(256)
void prepass(const float* __restrict__ K, const float* __restrict__ V,
             _Float16* __restrict__ K16F, _Float16* __restrict__ V16T2) {
  __shared__ float tile[32][128];
  const int tid  = threadIdx.x;
  const int tb   = blockIdx.x;     // 32-row k-tile, 0..63
  const int head = blockIdx.y;
  const size_t hb = (size_t)head * S * D;
  const float* Kt = K + hb + (size_t)tb * 32 * D;
  const float* Vt = V + hb + (size_t)tb * 32 * D;

#pragma unroll
  for (int it = 0; it < 4; ++it) {
    int idx = it * 256 + tid;
    int row = idx >> 5, c = idx & 31;
    *(float4*)&tile[row][c * 4] = *(const float4*)(Kt + (size_t)row * D + c * 4);
  }
  __syncthreads();
#pragma unroll
  for (int it = 0; it < 2; ++it) {
    int s = it * 256 + tid;
    int r = s & 31, g = s >> 5;
    int ds = g >> 1, hh = g & 1;
    int sr = (r & 19) | ((r & 4) << 1) | ((r & 8) >> 1);   // swap bits 2,3
    const float* src = &tile[sr][ds * 16 + 8 * hh];
    f16x8 o;
#pragma unroll
    for (int i = 0; i < 8; ++i) o[i] = (_Float16)src[i];
    *(f16x8*)(K16F + ((size_t)(head * 64 + tb) * 16 + g) * 256 + r * 8) = o;
  }
  __syncthreads();
#pragma unroll
  for (int it = 0; it < 4; ++it) {
    int idx = it * 256 + tid;
    int row = idx >> 5, c = idx & 31;
    *(float4*)&tile[row][c * 4] = *(const float4*)(Vt + (size_t)row * D + c * 4);
  }
  __syncthreads();
#pragma unroll
  for (int it = 0; it < 2; ++it) {
    int s = it * 256 + tid;
    int dd = s & 31, g = s >> 5;
    int hh = g & 1, dt = (g >> 1) & 3, kl = g >> 3;
    f16x8 o;
#pragma unroll
    for (int i = 0; i < 8; ++i) o[i] = (_Float16)tile[kl * 16 + 8 * hh + i][dt * 32 + dd];
    *(f16x8*)(V16T2 + (((size_t)(head * 128 + tb * 2 + kl) * 4 + dt) * 2 + hh) * 256 + dd * 8) = o;
  }
}

__global__ __launch_bounds__(512, 2)
void entmax_attn(const float* __restrict__ Q, const _Float16* __restrict__ K16F,
                 const _Float16* __restrict__ V16T2, float* __restrict__ O) {
  __shared__ __align__(16) char zbuf[131072];   // 32q x 4096B z rows; aliased as oreg
  __shared__ float taubuf[32];

  const int tid  = threadIdx.x;
  const int lane = tid & 63;
  const int wid  = tid >> 6;
  const int l31  = lane & 31;
  const int h    = lane >> 5;

  const int bi   = blockIdx.x;
  const int head = (bi & 7) * 2 + ((bi >> 3) >> 6);
  const int qb   = ((bi >> 3) & 63) * 32;

  const size_t hb = (size_t)head * S * D;
  const float* Qh = Q + hb;
  float* Oh = O + hb;

  const _Float16* kfp = K16F + ((size_t)(head * 64 + wid * 8)) * 4096 + lane * 8;
  const _Float16* vfp = V16T2 + ((size_t)(head * 128 + wid * 16)) * 2048 + lane * 8;

  const float hs = 0.04419417382415922f;  // 0.5 / sqrt(128)
  const v2h zero2 = {(_Float16)0.f, (_Float16)0.f};
  const v2h one2  = {(_Float16)1.f, (_Float16)1.f};

  // ---- Q fragments (hs folded): B[d][q], q=l31, d = ds*16 + 8h + i ----
  f16x8 qf[8];
  {
    const float* qr = Qh + (size_t)(qb + l31) * D + 8 * h;
#pragma unroll
    for (int ds = 0; ds < 8; ++ds) {
      float4 a = *(const float4*)(qr + ds * 16);
      float4 b = *(const float4*)(qr + ds * 16 + 4);
      a.x *= hs; a.y *= hs; a.z *= hs; a.w *= hs;
      b.x *= hs; b.y *= hs; b.z *= hs; b.w *= hs;
      qf[ds] = cvt8(a, b);
    }
  }

  // ---- Phase A: QK^T, coalesced K frags, 2-tile register double buffer ----
  f32x16 acc[8];
#pragma unroll
  for (int t = 0; t < 8; ++t)
#pragma unroll
    for (int e = 0; e < 16; ++e) acc[t][e] = 0.f;

  {
    f16x8 kA[8], kB[8];
#pragma unroll
    for (int ds = 0; ds < 8; ++ds) kA[ds] = *(const f16x8*)(kfp + 0 * 4096 + ds * 512);
#pragma unroll
    for (int ds = 0; ds < 8; ++ds) kB[ds] = *(const f16x8*)(kfp + 1 * 4096 + ds * 512);
#pragma unroll
    for (int t = 0; t < 8; t += 2) {
#pragma unroll
      for (int ds = 0; ds < 8; ++ds) {
        acc[t] = __builtin_amdgcn_mfma_f32_32x32x16_f16(kA[ds], qf[ds], acc[t], 0, 0, 0);
        if (t + 2 < 8) kA[ds] = *(const f16x8*)(kfp + (t + 2) * 4096 + ds * 512);
      }
#pragma unroll
      for (int ds = 0; ds < 8; ++ds) {
        acc[t + 1] = __builtin_amdgcn_mfma_f32_32x32x16_f16(kB[ds], qf[ds], acc[t + 1], 0, 0, 0);
        if (t + 3 < 8) kB[ds] = *(const f16x8*)(kfp + (t + 3) * 4096 + ds * 512);
      }
    }
  }

  // ---- z = acc (f16, NO max-sub); z.f8[kt] = 8 consecutive k at kt*16+8h ----
  Z z;
#pragma unroll
  for (int t = 0; t < 8; ++t)
#pragma unroll
    for (int j = 0; j < 8; ++j) {
      PK pk;
      pk.a = __builtin_amdgcn_cvt_pkrtz(acc[t][2 * j], acc[t][2 * j + 1]);
      z.v2[t * 8 + j] = pk.b;
    }

  // ---- Phase R: redistribute z -> zbuf (row q, swizzled) ----
  {
    const int sw = (l31 & 7) << 4;
#pragma unroll
    for (int kt = 0; kt < 16; ++kt) {
      const int by = l31 * 4096 + ((wid * 512 + kt * 32 + 16 * h) ^ sw);
      *(f16x8*)(zbuf + by) = z.f8[kt];
    }
  }
  __syncthreads();   // barrier 1

  // ---- Phase B: wave-local row max + 8 Newton iters on 4 complete rows ----
  {
    const int r = lane >> 4, c = lane & 15;
    const int q = wid * 4 + r;
    const int swq = (q & 7) << 4;
    Z zr;
#pragma unroll
    for (int j = 0; j < 16; ++j)
      zr.f8[j] = *(const f16x8*)(zbuf + q * 4096 + ((c * 256 + j * 16) ^ swq));

    v2h mv = zr.v2[0];
#pragma unroll
    for (int j = 1; j < 64; ++j) mv = __builtin_elementwise_max(mv, zr.v2[j]);
    float mx = fmaxf((float)mv[0], (float)mv[1]);
#pragma unroll
    for (int off = 8; off >= 1; off >>= 1) mx = fmaxf(mx, __shfl_xor(mx, off));

    float tau = mx - 1.f;
#pragma unroll
    for (int it = 0; it < 8; ++it) {
      const _Float16 th = (_Float16)tau;
      const v2h tt = {th, th};
      float f = 0.f, g = 0.f;
#pragma unroll
      for (int j = 0; j < 64; ++j) {
        v2h d = __builtin_elementwise_max(zr.v2[j] - tt, zero2);
#if __has_builtin(__builtin_amdgcn_fdot2)
        f = __builtin_amdgcn_fdot2(d, d, f, false);
        g = __builtin_amdgcn_fdot2(d, one2, g, false);
#else
        float d0 = (float)d[0], d1 = (float)d[1];
        f = fmaf(d0, d0, fmaf(d1, d1, f));
        g += d0 + d1;
#endif
      }
#pragma unroll
      for (int off = 8; off >= 1; off >>= 1) {
        f += __shfl_xor(f, off);
        g += __shfl_xor(g, off);
      }
      tau += (f - 1.f) / (2.f * fmaxf(g, 1e-20f));
    }
    if (c == 0) taubuf[q] = tau;
  }
  __syncthreads();   // barrier 2 (also: zbuf reads done -> oreg alias safe)

  // ---- Phase C: p = (z - tau)^2 in place (sigma-layout = PV B-frags) ----
  {
    const _Float16 th = (_Float16)taubuf[l31];
    const v2h tt = {th, th};
#pragma unroll
    for (int j = 0; j < 64; ++j) {
      v2h d = __builtin_elementwise_max(z.v2[j] - tt, zero2);
      z.v2[j] = d * d;
    }
  }

  // ---- Phase D: O^T partial = V^T P, all-register, V frags coalesced ----
  f32x16 oacc[4];
#pragma unroll
  for (int dt = 0; dt < 4; ++dt)
#pragma unroll
    for (int e = 0; e < 16; ++e) oacc[dt][e] = 0.f;

  {
    f16x8 vf0[4], vf1[4];
#pragma unroll
    for (int dt = 0; dt < 4; ++dt) vf0[dt] = *(const f16x8*)(vfp + 0 * 2048 + dt * 512);
#pragma unroll
    for (int kt = 0; kt < 16; ++kt) {
      f16x8* cur = (kt & 1) ? vf1 : vf0;
      f16x8* nxt = (kt & 1) ? vf0 : vf1;
#pragma unroll
      for (int dt = 0; dt < 4; ++dt) {
        if (kt < 15) nxt[dt] = *(const f16x8*)(vfp + (kt + 1) * 2048 + dt * 512);
        oacc[dt] = __builtin_amdgcn_mfma_f32_32x32x16_f16(cur[dt], z.f8[kt], oacc[dt], 0, 0, 0);
      }
    }
  }

  // ---- Phase E: 8-region partial write (oreg = zbuf alias) + coop sum ----
  {
    char* b = zbuf + wid * 16384;
#pragma unroll
    for (int dt = 0; dt < 4; ++dt)
#pragma unroll
      for (int eq = 0; eq < 4; ++eq) {
        int d0 = dt * 32 + 8 * eq + 4 * h;
        int by = l31 * 512 + ((d0 * 4) ^ ((l31 & 7) << 4));
        f32x4 v = {oacc[dt][eq * 4 + 0], oacc[dt][eq * 4 + 1],
                   oacc[dt][eq * 4 + 2], oacc[dt][eq * 4 + 3]};
        *(f32x4*)(b + by) = v;
      }
  }
  __syncthreads();   // barrier 3
  {
    int q = tid >> 4, dq = tid & 15;
    int by0 = q * 512 + ((dq * 32) ^ ((q & 7) << 4));
    int by1 = q * 512 + ((dq * 32 + 16) ^ ((q & 7) << 4));
    f32x4 s0 = {0.f, 0.f, 0.f, 0.f}, s1 = {0.f, 0.f, 0.f, 0.f};
#pragma unroll
    for (int r = 0; r < 8; ++r) {
      const char* b = zbuf + r * 16384;
      f32x4 v0 = *(const f32x4*)(b + by0);
      f32x4 v1 = *(const f32x4*)(b + by1);
#pragma unroll
      for (int c = 0; c < 4; ++c) { s0[c] += v0[c]; s1[c] += v1[c]; }
    }
    float* op = Oh + (size_t)(qb + q) * D + dq * 8;
    *(f32x4*)op = s0;
    *(f32x4*)(op + 4) = s1;
  }
}

extern "C" void kernel_launch(void* const* d_in, const int* in_sizes, int n_in,
                              void* d_out, int out_size, void* d_ws, size_t ws_size,
                              hipStream_t stream) {
  const float* q = (const float*)d_in[0];
  const float* k = (const float*)d_in[1];
  const float* v = (const float*)d_in[2];
  float* out = (float*)d_out;

  const size_t nelem = (size_t)NH * S * D;
  _Float16* k16f  = (_Float16*)d_ws;
  _Float16* v16t2 = k16f + nelem;

  prepass<<<dim3(S / 32, NH), dim3(256), 0, stream>>>(k, v, k16f, v16t2);
  entmax_attn<<<dim3(1024), dim3(512), 0, stream>>>(q, k16f, v16t2, out);
}